// Round 4
// baseline (532.285 us; speedup 1.0000x reference)
//
#include <hip/hip_runtime.h>

#define NQPTS 20000
#define NSUP  20000
#define NNB   30
#define NKP   15
#define KF    3840          // 15 * 256
#define EXTINV 20.0f        // 1 / 0.05

typedef __attribute__((ext_vector_type(4))) float f32x4;
typedef __attribute__((ext_vector_type(8))) short bf16x8;
typedef __attribute__((ext_vector_type(8))) unsigned short u16x8;

__device__ __forceinline__ unsigned short f2bf(float f){
  unsigned int u = __float_as_uint(f);
  u = (u + 0x7FFFu + ((u >> 16) & 1u)) >> 16;   // RNE
  return (unsigned short)u;
}

// ---------------------------------------------------------------------------
// weights f32 [3840][256]  ->  Bt bf16 [256][3840]  (transposed via LDS)
// ---------------------------------------------------------------------------
__global__ __launch_bounds__(256) void convert_wt(const float* __restrict__ W,
                                                  unsigned short* __restrict__ Bt){
  __shared__ unsigned short tile[64*130];
  const int kf0 = blockIdx.x * 128, o0 = blockIdx.y * 64;
  const int to = threadIdx.x & 63, tk = threadIdx.x >> 6;
  #pragma unroll
  for (int i = 0; i < 32; i++){
    int kf = i*4 + tk;
    tile[to*130 + kf] = f2bf(W[(size_t)(kf0+kf)*256 + o0 + to]);
  }
  __syncthreads();
  #pragma unroll
  for (int j = 0; j < 32; j++){
    int flat = threadIdx.x + j*256;
    int ol = flat >> 7, kl = flat & 127;
    Bt[(size_t)(o0+ol)*KF + kf0 + kl] = tile[ol*130 + kl];
  }
}

// ---------------------------------------------------------------------------
// Phase A+B v3: one query per block (4 waves split neighbors).
// lrf_features via MFMA: aligned_lrf -> A_q (bf16, K=64 padded, bias folded
// at u=36), WT = W_lrf^T bf16; per wave 8 MFMAs replace per-lane dot products.
// x-half of weighted MFMA B-fragments prefetched direct-to-register at block
// start (no LDS transpose). Weighted: D[k][c] = sum_m AW[k][m]*NX[m][c].
// ---------------------------------------------------------------------------
__global__ __launch_bounds__(256, 4) void build_weighted_v3(
    const float* __restrict__ q_pts, const float* __restrict__ s_pts,
    const int*   __restrict__ inds,  const float* __restrict__ x,
    const float* __restrict__ q_lrf, const float* __restrict__ s_lrf,
    const float* __restrict__ kp,    const float* __restrict__ Wlrf,
    const float* __restrict__ blrf,  unsigned short* __restrict__ wsA,
    int n0)
{
  __shared__ __align__(16) unsigned short A_q[4*32*64];  // [q][m][u swz] 16KB
  __shared__ __align__(16) unsigned short AWs[64*32];    // [q*16+k][m swz] 4KB
  __shared__ __align__(16) unsigned short NXT[4*32*32];  // [q][c0][m swz] 8KB
  __shared__ __align__(16) unsigned short WT[32*64];     // [c][u swz] 4KB
  __shared__ float slrf[4][36];

  const int tid = threadIdx.x;
  const int wid = tid >> 6, lane = tid & 63;
  const int fr = lane & 15, mg = lane >> 4;
  const int n = n0 + blockIdx.x;

  { // zero A_q (covers u=37..63 pad, m=30,31 pad) + AWs
    f32x4 z = {0.f,0.f,0.f,0.f};
    f32x4* p = (f32x4*)A_q;
    p[tid] = z; p[256+tid] = z; p[512+tid] = z; p[768+tid] = z;
    ((f32x4*)AWs)[tid] = z;
  }

  const float qp0 = q_pts[(size_t)n*3], qp1 = q_pts[(size_t)n*3+1], qp2 = q_pts[(size_t)n*3+2];
  int idxr = NSUP;
  if (lane < NNB) idxr = inds[(size_t)n*NNB + lane];

  // WT build: WT[c][u] = Wlrf[u][c]; u=36 -> bias; u>36 -> 0. XOR swz by c&7.
  {
    int c = tid & 31, u0 = (tid >> 5) * 8;
    #pragma unroll
    for (int i = 0; i < 8; i++){
      int u = u0 + i;
      float v = (u < 36) ? Wlrf[u*32 + c] : (u == 36 ? blrf[c] : 0.f);
      WT[c*64 + ((((u>>3) ^ (c&7)) << 3) | (u & 7))] = f2bf(v);
    }
  }

  // roles: aligned_lrf (3 rounds of 64 lanes cover v = q*36+u, 144 vals)
  int abase[3], asj[3], aug[3]; bool acta[3]; float qla[3][3];
  #pragma unroll
  for (int r = 0; r < 3; r++){
    int v = r*64 + lane;
    acta[r] = (v < 144);
    int vv = acta[r] ? v : 0;
    int q = vv/36, u = vv%36;
    int s = u/9, rem = u%9, ia = rem/3, ja = rem%3;
    asj[r]   = s*9 + ja;
    abase[r] = q*2048 + (u & 7);
    aug[r]   = u >> 3;
    #pragma unroll
    for (int k = 0; k < 3; k++)
      qla[r][k] = acta[r] ? q_lrf[(size_t)n*36 + q*9 + k*3 + ia] : 0.f;
  }
  // roles: kernel-point weights (lanes 0..59 -> (q,k))
  const int qw = (lane < 60) ? lane/15 : 0;
  const int kw = (lane < 60) ? lane%15 : 0;
  float qlw[9];
  #pragma unroll
  for (int t = 0; t < 9; t++) qlw[t] = q_lrf[(size_t)n*36 + qw*9 + t];
  const float kpx = kp[kw*3], kpy = kp[kw*3+1], kpz = kp[kw*3+2];
  const int awbase = (qw*16 + kw)*32, awx = (qw*16 + kw)&3;

  // x prefetch: B-frag values for weighted MFMA, nf=0,1 (x channels)
  float xv[16];
  #pragma unroll
  for (int nf = 0; nf < 2; nf++){
    int ch = wid*32 + nf*16 + fr;
    #pragma unroll
    for (int j = 0; j < 8; j++){
      int mm = mg*8 + j;
      int ix = __shfl(idxr, mm);
      int icx = ix < NSUP ? ix : 0;
      float v = x[(size_t)icx*128 + ch];
      xv[nf*8+j] = ix < NSUP ? v : 0.f;
    }
  }

  __syncthreads();   // zeros + WT visible

  for (int m = wid; m < NNB; m += 4){
    const int idx = __shfl(idxr, m);
    const bool val = (idx < NSUP);
    const int ic = val ? idx : 0;
    if (lane < 36){
      float sv = s_lrf[(size_t)ic*36 + lane];
      slrf[wid][lane] = val ? sv : 0.f;
    }
    float d0, d1, d2;
    if (val){ d0 = s_pts[(size_t)ic*3]-qp0; d1 = s_pts[(size_t)ic*3+1]-qp1; d2 = s_pts[(size_t)ic*3+2]-qp2; }
    else    { d0 = 1e6f-qp0; d1 = 1e6f-qp1; d2 = 1e6f-qp2; }   // shadow, same math as ref

    if (lane < 60){
      // kernel-point influence aw[q][k]
      float a0 = d0*qlw[0] + d1*qlw[3] + d2*qlw[6];
      float a1 = d0*qlw[1] + d1*qlw[4] + d2*qlw[7];
      float a2 = d0*qlw[2] + d1*qlw[5] + d2*qlw[8];
      float s0 = a0-kpx, s1 = a1-kpy, s2 = a2-kpz;
      float awv = fmaxf(0.f, 1.f - sqrtf(s0*s0+s1*s1+s2*s2)*EXTINV);
      AWs[awbase + ((((m>>3) ^ awx) << 3) | (m & 7))] = f2bf(awv);
    } else {
      // bias fold: A_q[q][m][36] = val ? 1 : 0  (u=36: group 4, low 4)
      int qq = lane - 60;
      A_q[qq*2048 + m*64 + (((4 ^ (m&7)) << 3) | 4)] = val ? (unsigned short)0x3F80 : (unsigned short)0;
    }

    asm volatile("s_waitcnt lgkmcnt(0)" ::: "memory");  // slrf visible (wave-internal)

    // aligned_lrf[q][s,i,j] = sum_k ql[q,k,i]*slrf[s,k,j] -> A_q bf16 (swz)
    #pragma unroll
    for (int r = 0; r < 3; r++){
      if (acta[r]){
        const float* sp = &slrf[wid][asj[r]];
        float acc = qla[r][0]*sp[0] + qla[r][1]*sp[3] + qla[r][2]*sp[6];
        A_q[abase[r] + m*64 + ((aug[r] ^ (m&7)) << 3)] = f2bf(acc);
      }
    }
  }

  __syncthreads();   // all A_q / AWs writes visible

  // lrf-features MFMA: wave wid handles q=wid. C_q[32 m][32 c] over K=64 (2 steps)
  f32x4 cq00 = {0,0,0,0}, cq01 = cq00, cq10 = cq00, cq11 = cq00;
  #pragma unroll
  for (int step = 0; step < 2; step++){
    int g = step*4 + mg;
    bf16x8 a0 = *(const bf16x8*)&A_q[wid*2048 + (fr     )*64 + ((g ^ (fr&7)) << 3)];
    bf16x8 a1 = *(const bf16x8*)&A_q[wid*2048 + (16 + fr)*64 + ((g ^ ((16+fr)&7)) << 3)];
    bf16x8 b0 = *(const bf16x8*)&WT[(fr     )*64 + ((g ^ (fr&7)) << 3)];
    bf16x8 b1 = *(const bf16x8*)&WT[(16 + fr)*64 + ((g ^ ((16+fr)&7)) << 3)];
    cq00 = __builtin_amdgcn_mfma_f32_16x16x32_bf16(a0, b0, cq00, 0, 0, 0);
    cq01 = __builtin_amdgcn_mfma_f32_16x16x32_bf16(a0, b1, cq01, 0, 0, 0);
    cq10 = __builtin_amdgcn_mfma_f32_16x16x32_bf16(a1, b0, cq10, 0, 0, 0);
    cq11 = __builtin_amdgcn_mfma_f32_16x16x32_bf16(a1, b1, cq11, 0, 0, 0);
  }
  // scatter C_q -> NXT[q][c0][m] (swz by c0&3); m=30,31 rows are zero (A_q pad)
  #pragma unroll
  for (int mt = 0; mt < 2; mt++){
    #pragma unroll
    for (int ct = 0; ct < 2; ct++){
      f32x4 cv = (mt==0) ? (ct==0 ? cq00 : cq01) : (ct==0 ? cq10 : cq11);
      #pragma unroll
      for (int r = 0; r < 4; r++){
        int mrow = mt*16 + mg*4 + r;        // C/D: col=lane&15, row=(lane>>4)*4+r
        int c0 = ct*16 + fr;
        NXT[wid*1024 + c0*32 + ((((mrow>>3) ^ (c0&3)) << 3) | (mrow & 7))] = f2bf(cv[r]);
      }
    }
  }

  // pack x prefetch into B-fragments
  bf16x8 xf[2];
  #pragma unroll
  for (int nf = 0; nf < 2; nf++)
    #pragma unroll
    for (int j = 0; j < 8; j++)
      ((unsigned short*)&xf[nf])[j] = f2bf(xv[nf*8+j]);

  asm volatile("s_waitcnt lgkmcnt(0)" ::: "memory");  // NXT scatter visible (wave-internal)

  // weighted MFMA: D[k][c] = sum_m AW[q*16+k][m] * NX[m][c]
  const int arow = wid*16 + fr;
  bf16x8 awf = *(const bf16x8*)&AWs[arow*32 + ((mg ^ (arow&3)) << 3)];
  const size_t base = (size_t)blockIdx.x * KF;
  #pragma unroll
  for (int nf = 0; nf < 4; nf++){
    bf16x8 bf_;
    if (nf < 2){
      bf_ = xf[nf];
    } else {
      int c0 = (nf-2)*16 + fr;
      bf_ = *(const bf16x8*)&NXT[wid*1024 + c0*32 + ((mg ^ (c0&3)) << 3)];
    }
    f32x4 z = {0,0,0,0};
    f32x4 d = __builtin_amdgcn_mfma_f32_16x16x32_bf16(awf, bf_, z, 0, 0, 0);
    #pragma unroll
    for (int r = 0; r < 4; r++){
      int k = mg*4 + r;
      if (k < NKP)
        wsA[base + k*256 + wid*64 + nf*16 + fr] = f2bf(d[r]);
    }
  }
}

// ---------------------------------------------------------------------------
// Phase C v3: no-LDS direct-to-register GEMM. BM=64, BN=256, 4 waves
// (wave = 64 rows x 64 cols), 2-deep register ping-pong, no barriers.
// A streams once from HBM; B (2MB) is L2-resident.
// ---------------------------------------------------------------------------
__global__ __launch_bounds__(256, 3) void gemm_out_v3(
    const unsigned short* __restrict__ A,   // [padM][3840] bf16
    const unsigned short* __restrict__ Bt,  // [256][3840] bf16
    const float* __restrict__ bias,
    float* __restrict__ out, int n0)
{
  const int tid = threadIdx.x, lane = tid & 63, wid = tid >> 6;
  const int fr = lane & 15, mg = lane >> 4;
  const int m0 = blockIdx.x * 64;

  const unsigned short* aB = A  + (size_t)(m0 + fr)*KF + mg*8;
  const unsigned short* bB = Bt + (size_t)(wid*64 + fr)*KF + mg*8;

  f32x4 acc[4][4];
  #pragma unroll
  for (int i = 0; i < 4; i++)
    #pragma unroll
    for (int j = 0; j < 4; j++){ f32x4 z = {0,0,0,0}; acc[i][j] = z; }

  bf16x8 aX[4], bX[4], aY[4], bY[4];

  #define LDFR(av, bv, k0)                                                   \
    do {                                                                     \
      _Pragma("unroll")                                                      \
      for (int mf = 0; mf < 4; mf++)                                         \
        av[mf] = *(const bf16x8*)(aB + (size_t)mf*16*KF + (k0));             \
      _Pragma("unroll")                                                      \
      for (int nf = 0; nf < 4; nf++)                                         \
        bv[nf] = *(const bf16x8*)(bB + (size_t)nf*16*KF + (k0));             \
    } while (0)

  #define MM(av, bv)                                                         \
    do {                                                                     \
      _Pragma("unroll")                                                      \
      for (int mf = 0; mf < 4; mf++)                                         \
        _Pragma("unroll")                                                    \
        for (int nf = 0; nf < 4; nf++)                                       \
          acc[mf][nf] = __builtin_amdgcn_mfma_f32_16x16x32_bf16(av[mf], bv[nf], acc[mf][nf], 0, 0, 0); \
    } while (0)

  LDFR(aX, bX, 0);
  for (int t = 0; t < 120; t += 2){
    LDFR(aY, bY, (t+1)*32);
    MM(aX, bX);
    if (t + 2 < 120) LDFR(aX, bX, (t+2)*32);
    MM(aY, bY);
  }
  #undef LDFR
  #undef MM

  float bv4[4];
  #pragma unroll
  for (int nf = 0; nf < 4; nf++) bv4[nf] = bias[wid*64 + nf*16 + fr];
  #pragma unroll
  for (int mf = 0; mf < 4; mf++){
    #pragma unroll
    for (int nf = 0; nf < 4; nf++){
      #pragma unroll
      for (int r = 0; r < 4; r++){
        int row = mf*16 + mg*4 + r;          // C/D: col=lane&15, row=(lane>>4)*4+r
        int n_g = n0 + m0 + row;
        if (n_g < NQPTS){
          int o = wid*64 + nf*16 + fr;
          float v = acc[mf][nf][r] + bv4[nf];
          out[(size_t)n_g*256 + o] = (v >= 0.f) ? v : 0.1f*v;
        }
      }
    }
  }
}

// ---------------------------------------------------------------------------
extern "C" void kernel_launch(void* const* d_in, const int* in_sizes, int n_in,
                              void* d_out, int out_size, void* d_ws, size_t ws_size,
                              hipStream_t stream)
{
  const float* q_pts = (const float*)d_in[0];
  const float* s_pts = (const float*)d_in[1];
  const int*   inds  = (const int*)  d_in[2];
  const float* x     = (const float*)d_in[3];
  const float* q_lrf = (const float*)d_in[4];
  const float* s_lrf = (const float*)d_in[5];
  const float* kp    = (const float*)d_in[6];
  const float* wts   = (const float*)d_in[7];
  const float* Wlrf  = (const float*)d_in[8];
  const float* blrf  = (const float*)d_in[9];
  const float* bias  = (const float*)d_in[10];
  float* out = (float*)d_out;

  const size_t BBYTES = (size_t)256 * KF * sizeof(unsigned short); // 1.97 MB
  unsigned short* wsB = (unsigned short*)d_ws;
  unsigned short* wsA = (unsigned short*)((char*)d_ws + BBYTES);

  size_t avail = (ws_size > BBYTES) ? (ws_size - BBYTES) : 0;
  long maxRows = (long)(avail / ((size_t)KF * sizeof(unsigned short)));
  long chunk = (maxRows / 128) * 128;
  if (chunk > 20096) chunk = 20096;
  if (chunk < 128)   chunk = 128;   // last-resort; assumes ws >= ~2.5 MB

  convert_wt<<<dim3(30, 4), 256, 0, stream>>>(wts, wsB);

  for (long n0 = 0; n0 < NQPTS; n0 += chunk){
    long rows = NQPTS - n0; if (rows > chunk) rows = chunk;
    long padM = ((rows + 63)/64)*64;
    build_weighted_v3<<<(int)rows, 256, 0, stream>>>(q_pts, s_pts, inds, x,
        q_lrf, s_lrf, kp, Wlrf, blrf, wsA, (int)n0);
    gemm_out_v3<<<(int)(padM/64), 256, 0, stream>>>(wsA, wsB, bias, out, (int)n0);
  }
}

// Round 5
// 408.427 us; speedup vs baseline: 1.3033x; 1.3033x over previous
//
#include <hip/hip_runtime.h>

#define NQPTS 20000
#define NSUP  20000
#define NNB   30
#define NKP   15
#define KF    3840          // 15 * 256
#define KC    1920          // per-k-group chunk in gemm
#define EXTINV 20.0f        // 1 / 0.05

typedef __attribute__((ext_vector_type(4))) float f32x4;
typedef __attribute__((ext_vector_type(8))) short bf16x8;
typedef __attribute__((ext_vector_type(8))) unsigned short u16x8;

typedef __attribute__((address_space(1))) const unsigned int as1_u32;
typedef __attribute__((address_space(3))) unsigned int as3_u32;

__device__ __forceinline__ unsigned short f2bf(float f){
  unsigned int u = __float_as_uint(f);
  u = (u + 0x7FFFu + ((u >> 16) & 1u)) >> 16;   // RNE
  return (unsigned short)u;
}

__device__ __forceinline__ void gl_lds16(const unsigned short* g, unsigned short* l){
  __builtin_amdgcn_global_load_lds((as1_u32*)g, (as3_u32*)l, 16, 0, 0);
}

// ---------------------------------------------------------------------------
// weights f32 [3840][256]  ->  Bt bf16 [256][3840]  (transposed via LDS)
// ---------------------------------------------------------------------------
__global__ __launch_bounds__(256) void convert_wt(const float* __restrict__ W,
                                                  unsigned short* __restrict__ Bt){
  __shared__ unsigned short tile[64*130];
  const int kf0 = blockIdx.x * 128, o0 = blockIdx.y * 64;
  const int to = threadIdx.x & 63, tk = threadIdx.x >> 6;
  #pragma unroll
  for (int i = 0; i < 32; i++){
    int kf = i*4 + tk;
    tile[to*130 + kf] = f2bf(W[(size_t)(kf0+kf)*256 + o0 + to]);
  }
  __syncthreads();
  #pragma unroll
  for (int j = 0; j < 32; j++){
    int flat = threadIdx.x + j*256;
    int ol = flat >> 7, kl = flat & 127;
    Bt[(size_t)(o0+ol)*KF + kf0 + kl] = tile[ol*130 + kl];
  }
}

// ---------------------------------------------------------------------------
// Phase A+B v4: one query per block (4 waves split neighbors).
// ALL neighbor data (s_lrf, s_pts) prefetched cooperatively into LDS at block
// start -> the neighbor loop touches no global memory and has no waitcnt
// drains. lrf_features + weighted both via MFMA (as v3).
// ---------------------------------------------------------------------------
__global__ __launch_bounds__(256, 4) void build_weighted_v4(
    const float* __restrict__ q_pts, const float* __restrict__ s_pts,
    const int*   __restrict__ inds,  const float* __restrict__ x,
    const float* __restrict__ q_lrf, const float* __restrict__ s_lrf,
    const float* __restrict__ kp,    const float* __restrict__ Wlrf,
    const float* __restrict__ blrf,  unsigned short* __restrict__ wsA,
    int n0)
{
  __shared__ __align__(16) unsigned short A_q[4*32*64];  // [q][m][u swz] 16KB
  __shared__ __align__(16) unsigned short AWs[64*32];    // [q*16+k][m swz] 4KB
  __shared__ __align__(16) unsigned short NXT[4*32*32];  // [q][c0][m swz] 8KB
  __shared__ __align__(16) unsigned short WT[32*64];     // [c][u swz] 4KB
  __shared__ float slrfA[NNB*36];                        // [m][u] 4.3KB
  __shared__ float sptsA[NNB*4];                         // [m][c] 480B

  const int tid = threadIdx.x;
  const int wid = tid >> 6, lane = tid & 63;
  const int fr = lane & 15, mg = lane >> 4;
  const int n = n0 + blockIdx.x;

  { // zero A_q (covers u=37..63 pad, m=30,31 pad) + AWs
    f32x4 z = {0.f,0.f,0.f,0.f};
    f32x4* p = (f32x4*)A_q;
    p[tid] = z; p[256+tid] = z; p[512+tid] = z; p[768+tid] = z;
    ((f32x4*)AWs)[tid] = z;
  }

  const float qp0 = q_pts[(size_t)n*3], qp1 = q_pts[(size_t)n*3+1], qp2 = q_pts[(size_t)n*3+2];
  int idxr = NSUP;
  if (lane < NNB) idxr = inds[(size_t)n*NNB + lane];

  // cooperative prefetch: all neighbors' s_lrf -> LDS (shadow rows zeroed)
  for (int e = tid; e < NNB*36; e += 256){
    int m = e / 36, u = e - m*36;
    int ix = inds[(size_t)n*NNB + m];
    slrfA[e] = (ix < NSUP) ? s_lrf[(size_t)ix*36 + u] : 0.f;
  }
  // cooperative prefetch: s_pts (shadow -> 1e6, same math as ref)
  if (tid < NNB*4){
    int m = tid >> 2, c = tid & 3;
    if (c < 3){
      int ix = inds[(size_t)n*NNB + m];
      sptsA[tid] = (ix < NSUP) ? s_pts[(size_t)ix*3 + c] : 1e6f;
    }
  }

  // WT build: WT[c][u] = Wlrf[u][c]; u=36 -> bias; u>36 -> 0. XOR swz by c&7.
  {
    int c = tid & 31, u0 = (tid >> 5) * 8;
    #pragma unroll
    for (int i = 0; i < 8; i++){
      int u = u0 + i;
      float v = (u < 36) ? Wlrf[u*32 + c] : (u == 36 ? blrf[c] : 0.f);
      WT[c*64 + ((((u>>3) ^ (c&7)) << 3) | (u & 7))] = f2bf(v);
    }
  }

  // roles: aligned_lrf (3 rounds of 64 lanes cover v = q*36+u, 144 vals)
  int abase[3], asj[3], aug[3]; bool acta[3]; float qla[3][3];
  #pragma unroll
  for (int r = 0; r < 3; r++){
    int v = r*64 + lane;
    acta[r] = (v < 144);
    int vv = acta[r] ? v : 0;
    int q = vv/36, u = vv%36;
    int s = u/9, rem = u%9, ia = rem/3, ja = rem%3;
    asj[r]   = s*9 + ja;
    abase[r] = q*2048 + (u & 7);
    aug[r]   = u >> 3;
    #pragma unroll
    for (int k = 0; k < 3; k++)
      qla[r][k] = acta[r] ? q_lrf[(size_t)n*36 + q*9 + k*3 + ia] : 0.f;
  }
  // roles: kernel-point weights (lanes 0..59 -> (q,k))
  const int qw = (lane < 60) ? lane/15 : 0;
  const int kw = (lane < 60) ? lane%15 : 0;
  float qlw[9];
  #pragma unroll
  for (int t = 0; t < 9; t++) qlw[t] = q_lrf[(size_t)n*36 + qw*9 + t];
  const float kpx = kp[kw*3], kpy = kp[kw*3+1], kpz = kp[kw*3+2];
  const int awbase = (qw*16 + kw)*32, awx = (qw*16 + kw)&3;

  // x prefetch: B-frag values for weighted MFMA, nf=0,1 (x channels)
  float xv[16];
  #pragma unroll
  for (int nf = 0; nf < 2; nf++){
    int ch = wid*32 + nf*16 + fr;
    #pragma unroll
    for (int j = 0; j < 8; j++){
      int mm = mg*8 + j;
      int ix = __shfl(idxr, mm);
      int icx = ix < NSUP ? ix : 0;
      float v = x[(size_t)icx*128 + ch];
      xv[nf*8+j] = ix < NSUP ? v : 0.f;
    }
  }

  __syncthreads();   // zeros + WT + slrfA + sptsA visible

  // neighbor loop: no global access, no waitcnt drains
  for (int m = wid; m < NNB; m += 4){
    const int idx = __shfl(idxr, m);
    const bool val = (idx < NSUP);
    const float d0 = sptsA[m*4+0] - qp0;
    const float d1 = sptsA[m*4+1] - qp1;
    const float d2 = sptsA[m*4+2] - qp2;

    if (lane < 60){
      // kernel-point influence aw[q][k]
      float a0 = d0*qlw[0] + d1*qlw[3] + d2*qlw[6];
      float a1 = d0*qlw[1] + d1*qlw[4] + d2*qlw[7];
      float a2 = d0*qlw[2] + d1*qlw[5] + d2*qlw[8];
      float s0 = a0-kpx, s1 = a1-kpy, s2 = a2-kpz;
      float awv = fmaxf(0.f, 1.f - sqrtf(s0*s0+s1*s1+s2*s2)*EXTINV);
      AWs[awbase + ((((m>>3) ^ awx) << 3) | (m & 7))] = f2bf(awv);
    } else {
      // bias fold: A_q[q][m][36] = val ? 1 : 0  (u=36: group 4, low 4)
      int qq = lane - 60;
      A_q[qq*2048 + m*64 + (((4 ^ (m&7)) << 3) | 4)] = val ? (unsigned short)0x3F80 : (unsigned short)0;
    }

    // aligned_lrf[q][s,i,j] = sum_k ql[q,k,i]*slrf[s,k,j] -> A_q bf16 (swz)
    #pragma unroll
    for (int r = 0; r < 3; r++){
      if (acta[r]){
        const float* sp = &slrfA[m*36 + asj[r]];
        float acc = qla[r][0]*sp[0] + qla[r][1]*sp[3] + qla[r][2]*sp[6];
        A_q[abase[r] + m*64 + ((aug[r] ^ (m&7)) << 3)] = f2bf(acc);
      }
    }
  }

  __syncthreads();   // all A_q / AWs writes visible

  // lrf-features MFMA: wave wid handles q=wid. C_q[32 m][32 c] over K=64 (2 steps)
  f32x4 cq00 = {0,0,0,0}, cq01 = cq00, cq10 = cq00, cq11 = cq00;
  #pragma unroll
  for (int step = 0; step < 2; step++){
    int g = step*4 + mg;
    bf16x8 a0 = *(const bf16x8*)&A_q[wid*2048 + (fr     )*64 + ((g ^ (fr&7)) << 3)];
    bf16x8 a1 = *(const bf16x8*)&A_q[wid*2048 + (16 + fr)*64 + ((g ^ ((16+fr)&7)) << 3)];
    bf16x8 b0 = *(const bf16x8*)&WT[(fr     )*64 + ((g ^ (fr&7)) << 3)];
    bf16x8 b1 = *(const bf16x8*)&WT[(16 + fr)*64 + ((g ^ ((16+fr)&7)) << 3)];
    cq00 = __builtin_amdgcn_mfma_f32_16x16x32_bf16(a0, b0, cq00, 0, 0, 0);
    cq01 = __builtin_amdgcn_mfma_f32_16x16x32_bf16(a0, b1, cq01, 0, 0, 0);
    cq10 = __builtin_amdgcn_mfma_f32_16x16x32_bf16(a1, b0, cq10, 0, 0, 0);
    cq11 = __builtin_amdgcn_mfma_f32_16x16x32_bf16(a1, b1, cq11, 0, 0, 0);
  }
  // scatter C_q -> NXT[q][c0][m] (swz by c0&3); m=30,31 rows are zero (A_q pad)
  #pragma unroll
  for (int mt = 0; mt < 2; mt++){
    #pragma unroll
    for (int ct = 0; ct < 2; ct++){
      f32x4 cv = (mt==0) ? (ct==0 ? cq00 : cq01) : (ct==0 ? cq10 : cq11);
      #pragma unroll
      for (int r = 0; r < 4; r++){
        int mrow = mt*16 + mg*4 + r;        // C/D: col=lane&15, row=(lane>>4)*4+r
        int c0 = ct*16 + fr;
        NXT[wid*1024 + c0*32 + ((((mrow>>3) ^ (c0&3)) << 3) | (mrow & 7))] = f2bf(cv[r]);
      }
    }
  }

  // pack x prefetch into B-fragments
  bf16x8 xf[2];
  #pragma unroll
  for (int nf = 0; nf < 2; nf++)
    #pragma unroll
    for (int j = 0; j < 8; j++)
      ((unsigned short*)&xf[nf])[j] = f2bf(xv[nf*8+j]);

  asm volatile("s_waitcnt lgkmcnt(0)" ::: "memory");  // NXT scatter visible (wave-internal)

  // weighted MFMA: D[k][c] = sum_m AW[q*16+k][m] * NX[m][c]
  const int arow = wid*16 + fr;
  bf16x8 awf = *(const bf16x8*)&AWs[arow*32 + ((mg ^ (arow&3)) << 3)];
  const size_t base = (size_t)blockIdx.x * KF;
  #pragma unroll
  for (int nf = 0; nf < 4; nf++){
    bf16x8 bf_;
    if (nf < 2){
      bf_ = xf[nf];
    } else {
      int c0 = (nf-2)*16 + fr;
      bf_ = *(const bf16x8*)&NXT[wid*1024 + c0*32 + ((mg ^ (c0&3)) << 3)];
    }
    f32x4 z = {0,0,0,0};
    f32x4 d = __builtin_amdgcn_mfma_f32_16x16x32_bf16(awf, bf_, z, 0, 0, 0);
    #pragma unroll
    for (int r = 0; r < 4; r++){
      int k = mg*4 + r;
      if (k < NKP)
        wsA[base + k*256 + wid*64 + nf*16 + fr] = f2bf(d[r]);
    }
  }
}

// ---------------------------------------------------------------------------
// Phase C v4: BM=64, BN=256, 512 threads = 2 k-groups x 4 waves.
// Group g covers kf in [g*1920, (g+1)*1920), each with its own double-buffered
// LDS + global_load_lds staging (v2 structure). Epilogue: group 1 dumps acc
// to LDS, group 0 reduces + bias + leaky + store.
// ---------------------------------------------------------------------------
__global__ __launch_bounds__(512, 4) void gemm_out_v4(
    const unsigned short* __restrict__ A,   // [padM][3840] bf16
    const unsigned short* __restrict__ Bt,  // [256][3840] bf16
    const float* __restrict__ bias,
    float* __restrict__ out, int n0)
{
  __shared__ __align__(16) unsigned short As[2][2][64*32];    // 16KB
  __shared__ __align__(16) unsigned short Bs[2][2][256*32];   // 64KB
  const int tid = threadIdx.x, lane = tid & 63;
  const int w  = tid >> 6;
  const int g  = w >> 2;          // k-group
  const int wg = w & 3;           // col group (64 cols)
  const int t2 = tid & 255;
  const int fr = lane & 15, mg = lane >> 4;
  const int m0 = blockIdx.x * 64;
  const int gk0 = g * KC;

  const unsigned short* aSrc = A  + (size_t)(m0 + (t2>>2))*KF + gk0 + (t2&3)*8;
  const unsigned short* bSrc = Bt + (size_t)(t2>>2)*KF + gk0 + (t2&3)*8;

  f32x4 acc[4][4];
  #pragma unroll
  for (int i = 0; i < 4; i++)
    #pragma unroll
    for (int j = 0; j < 4; j++){ f32x4 z = {0,0,0,0}; acc[i][j] = z; }

  const int afo = fr*32 + mg*8;               // + mf*512
  const int bfo = (wg*64 + fr)*32 + mg*8;     // + nf*512

  #define STG(buf, k0)                                                       \
    do {                                                                     \
      gl_lds16(aSrc + (k0), &As[g][buf][t2*8]);                              \
      gl_lds16(bSrc + (size_t)0*64*KF + (k0), &Bs[g][buf][0*2048 + t2*8]);   \
      gl_lds16(bSrc + (size_t)1*64*KF + (k0), &Bs[g][buf][1*2048 + t2*8]);   \
      gl_lds16(bSrc + (size_t)2*64*KF + (k0), &Bs[g][buf][2*2048 + t2*8]);   \
      gl_lds16(bSrc + (size_t)3*64*KF + (k0), &Bs[g][buf][3*2048 + t2*8]);   \
    } while (0)

  STG(0, 0);
  asm volatile("s_waitcnt vmcnt(0)" ::: "memory");
  __syncthreads();

  int cur = 0;
  for (int t = 0; t < KC/32; ++t){
    if (t + 1 < KC/32) STG(cur^1, (t+1)*32);
    bf16x8 af[4], bf[4];
    #pragma unroll
    for (int mf = 0; mf < 4; mf++) af[mf] = *(const bf16x8*)&As[g][cur][afo + mf*512];
    #pragma unroll
    for (int nf = 0; nf < 4; nf++) bf[nf] = *(const bf16x8*)&Bs[g][cur][bfo + nf*512];
    #pragma unroll
    for (int mf = 0; mf < 4; mf++)
      #pragma unroll
      for (int nf = 0; nf < 4; nf++)
        acc[mf][nf] = __builtin_amdgcn_mfma_f32_16x16x32_bf16(af[mf], bf[nf], acc[mf][nf], 0, 0, 0);
    asm volatile("s_waitcnt vmcnt(0)" ::: "memory");
    __syncthreads();
    cur ^= 1;
  }
  #undef STG

  // cross-group reduce via LDS (reuse Bs: 64KB = 64x256 fp32)
  float* Cred = (float*)&Bs[0][0][0];
  if (g == 1){
    #pragma unroll
    for (int mf = 0; mf < 4; mf++)
      #pragma unroll
      for (int nf = 0; nf < 4; nf++)
        #pragma unroll
        for (int r = 0; r < 4; r++)
          Cred[(mf*16 + mg*4 + r)*256 + wg*64 + nf*16 + fr] = acc[mf][nf][r];
  }
  __syncthreads();
  if (g == 0){
    float bv4[4];
    #pragma unroll
    for (int nf = 0; nf < 4; nf++) bv4[nf] = bias[wg*64 + nf*16 + fr];
    #pragma unroll
    for (int mf = 0; mf < 4; mf++){
      #pragma unroll
      for (int nf = 0; nf < 4; nf++){
        #pragma unroll
        for (int r = 0; r < 4; r++){
          int row = mf*16 + mg*4 + r;          // C/D: col=lane&15, row=(lane>>4)*4+r
          int n_g = n0 + m0 + row;
          if (n_g < NQPTS){
            int o = wg*64 + nf*16 + fr;
            float v = acc[mf][nf][r] + Cred[row*256 + o] + bv4[nf];
            out[(size_t)n_g*256 + o] = (v >= 0.f) ? v : 0.1f*v;
          }
        }
      }
    }
  }
}

// ---------------------------------------------------------------------------
extern "C" void kernel_launch(void* const* d_in, const int* in_sizes, int n_in,
                              void* d_out, int out_size, void* d_ws, size_t ws_size,
                              hipStream_t stream)
{
  const float* q_pts = (const float*)d_in[0];
  const float* s_pts = (const float*)d_in[1];
  const int*   inds  = (const int*)  d_in[2];
  const float* x     = (const float*)d_in[3];
  const float* q_lrf = (const float*)d_in[4];
  const float* s_lrf = (const float*)d_in[5];
  const float* kp    = (const float*)d_in[6];
  const float* wts   = (const float*)d_in[7];
  const float* Wlrf  = (const float*)d_in[8];
  const float* blrf  = (const float*)d_in[9];
  const float* bias  = (const float*)d_in[10];
  float* out = (float*)d_out;

  const size_t BBYTES = (size_t)256 * KF * sizeof(unsigned short); // 1.97 MB
  unsigned short* wsB = (unsigned short*)d_ws;
  unsigned short* wsA = (unsigned short*)((char*)d_ws + BBYTES);

  size_t avail = (ws_size > BBYTES) ? (ws_size - BBYTES) : 0;
  long maxRows = (long)(avail / ((size_t)KF * sizeof(unsigned short)));
  long chunk = (maxRows / 128) * 128;
  if (chunk > 20096) chunk = 20096;
  if (chunk < 128)   chunk = 128;   // last-resort; assumes ws >= ~2.5 MB

  convert_wt<<<dim3(30, 4), 256, 0, stream>>>(wts, wsB);

  for (long n0 = 0; n0 < NQPTS; n0 += chunk){
    long rows = NQPTS - n0; if (rows > chunk) rows = chunk;
    long padM = ((rows + 63)/64)*64;
    build_weighted_v4<<<(int)rows, 256, 0, stream>>>(q_pts, s_pts, inds, x,
        q_lrf, s_lrf, kp, Wlrf, blrf, wsA, (int)n0);
    gemm_out_v4<<<(int)(padM/64), 512, 0, stream>>>(wsA, wsB, bias, out, (int)n0);
  }
}

// Round 7
// 372.290 us; speedup vs baseline: 1.4298x; 1.0971x over previous
//
#include <hip/hip_runtime.h>
#include <hip/hip_bf16.h>

#define NQPTS 20000
#define NSUP  20000
#define NNB   30
#define NKP   15
#define KF    3840          // 15 * 256
#define EXTINV 20.0f        // 1 / 0.05

typedef __attribute__((ext_vector_type(4))) float f32x4;
typedef __attribute__((ext_vector_type(8))) short bf16x8;
typedef __attribute__((ext_vector_type(8))) unsigned short u16x8;

typedef __attribute__((address_space(1))) const unsigned int as1_u32;
typedef __attribute__((address_space(3))) unsigned int as3_u32;

__device__ __forceinline__ unsigned short f2bf(float f){
  __hip_bfloat16 h = __float2bfloat16(f);          // native cvt (v_cvt_pk capable)
  return __builtin_bit_cast(unsigned short, h);
}
__device__ __forceinline__ float bf2f(unsigned short u){
  return __uint_as_float(((unsigned int)u) << 16);
}
__device__ __forceinline__ void gl_lds16(const unsigned short* g, unsigned short* l){
  __builtin_amdgcn_global_load_lds((as1_u32*)g, (as3_u32*)l, 16, 0, 0);
}

// ---------------------------------------------------------------------------
// weights f32 [3840][256] -> Bt bf16 [256][3840]
// ---------------------------------------------------------------------------
__global__ __launch_bounds__(256) void convert_wt(const float* __restrict__ W,
                                                  unsigned short* __restrict__ Bt){
  __shared__ unsigned short tile[64*130];
  const int kf0 = blockIdx.x * 128, o0 = blockIdx.y * 64;
  const int to = threadIdx.x & 63, tk = threadIdx.x >> 6;
  #pragma unroll
  for (int i = 0; i < 32; i++){
    int kf = i*4 + tk;
    tile[to*130 + kf] = f2bf(W[(size_t)(kf0+kf)*256 + o0 + to]);
  }
  __syncthreads();
  #pragma unroll
  for (int j = 0; j < 32; j++){
    int flat = threadIdx.x + j*256;
    int ol = flat >> 7, kl = flat & 127;
    Bt[(size_t)(o0+ol)*KF + kf0 + kl] = tile[ol*130 + kl];
  }
}

// ---------------------------------------------------------------------------
// W_lrf B-fragments, precomputed once (query-independent).
// wtf[((step*2+half)*64 + lane)*8 + j] = WT[c=half*16+(lane&15)][u=step*32+(lane>>4)*8+j]
// where WT[c][u] = Wlrf[u][c] (u<36), blrf[c] (u==36), 0 (u>36).
// ---------------------------------------------------------------------------
__global__ __launch_bounds__(64) void prep_wtfrag(const float* __restrict__ Wlrf,
                                                  const float* __restrict__ blrf,
                                                  unsigned short* __restrict__ wtf){
  const int lane = threadIdx.x, fr = lane & 15, mg = lane >> 4;
  #pragma unroll
  for (int step = 0; step < 2; step++){
    #pragma unroll
    for (int half = 0; half < 2; half++){
      int c = half*16 + fr;
      #pragma unroll
      for (int j = 0; j < 8; j++){
        int u = step*32 + mg*8 + j;
        float v = (u < 36) ? Wlrf[u*32 + c] : (u == 36 ? blrf[c] : 0.f);
        wtf[((size_t)(step*2+half)*64 + lane)*8 + j] = f2bf(v);
      }
    }
  }
}

// ---------------------------------------------------------------------------
// Phase A+B v5: one query per block, 4 waves split neighbors.
// LDS ~31KB -> 5 blocks/CU. WT frags from global (precomputed), q_lrf via
// one load + shfl, native bf16 cvts, static 8-iter neighbor loop.
// ---------------------------------------------------------------------------
__global__ __launch_bounds__(256, 5) void build_weighted_v5(
    const float* __restrict__ q_pts, const float* __restrict__ s_pts,
    const int*   __restrict__ inds,  const float* __restrict__ x,
    const float* __restrict__ q_lrf, const float* __restrict__ s_lrf,
    const float* __restrict__ kp,    const unsigned short* __restrict__ wtf,
    unsigned short* __restrict__ wsA, int n0)
{
  __shared__ __align__(16) unsigned short A_q[4*32*64];  // [q][m][u swz] 16KB
  __shared__ __align__(16) unsigned short AWs[64*32];    // [q*16+k][m swz] 4KB
  __shared__ __align__(16) unsigned short NXT[4*32*32];  // [q][c0][m swz] 8KB
  __shared__ unsigned short slrfA[NNB*36];               // [m][u] bf16 2.1KB
  __shared__ __align__(16) float sptsA[NNB*4];           // [m][c] 480B

  const int tid = threadIdx.x;
  const int wid = tid >> 6, lane = tid & 63;
  const int fr = lane & 15, mg = lane >> 4;
  const int n = n0 + blockIdx.x;

  // WT B-fragments: 4 global b128 loads (L2-hot), issued first
  bf16x8 wtb[2][2];
  #pragma unroll
  for (int s = 0; s < 2; s++)
    #pragma unroll
    for (int h = 0; h < 2; h++)
      wtb[s][h] = *(const bf16x8*)&wtf[((size_t)(s*2+h)*64 + lane)*8];

  { // zero A_q (covers u pad, m=30,31 pad) + AWs
    f32x4 z = {0.f,0.f,0.f,0.f};
    f32x4* p = (f32x4*)A_q;
    p[tid] = z; p[256+tid] = z; p[512+tid] = z; p[768+tid] = z;
    ((f32x4*)AWs)[tid] = z;
  }

  const float qp0 = q_pts[(size_t)n*3], qp1 = q_pts[(size_t)n*3+1], qp2 = q_pts[(size_t)n*3+2];
  int idxr = NSUP;
  if (lane < NNB) idxr = inds[(size_t)n*NNB + lane];

  // q_lrf: one element per lane, distribute via shfl
  const float qv = (lane < 36) ? q_lrf[(size_t)n*36 + lane] : 0.f;

  // roles: aligned_lrf (3 rounds cover v = q*36+u, 144 vals)
  int abase[3], asj[3], aug[3]; bool acta[3]; float qla[3][3];
  #pragma unroll
  for (int r = 0; r < 3; r++){
    int v = r*64 + lane;
    acta[r] = (v < 144);
    int vv = acta[r] ? v : 0;
    int q = vv/36, u = vv%36;
    int s = u/9, rem = u%9, ia = rem/3, ja = rem%3;
    asj[r]   = s*9 + ja;
    abase[r] = q*2048 + (u & 7);
    aug[r]   = u >> 3;
    #pragma unroll
    for (int k = 0; k < 3; k++)
      qla[r][k] = __shfl(qv, q*9 + k*3 + ia);
  }
  // roles: kernel-point weights (lanes 0..59 -> (q,k))
  const int qw = (lane < 60) ? lane/15 : 0;
  const int kw = (lane < 60) ? lane%15 : 0;
  float qlw[9];
  #pragma unroll
  for (int t = 0; t < 9; t++) qlw[t] = __shfl(qv, qw*9 + t);
  const float kpx = kp[kw*3], kpy = kp[kw*3+1], kpz = kp[kw*3+2];
  const int awbase = (qw*16 + kw)*32, awx = (qw*16 + kw)&3;

  // cooperative prefetch: s_lrf -> LDS bf16 (shadow rows zero)
  for (int e = tid; e < NNB*36; e += 256){
    int m = e / 36, u = e - m*36;
    int ix = inds[(size_t)n*NNB + m];
    slrfA[e] = (ix < NSUP) ? f2bf(s_lrf[(size_t)ix*36 + u]) : (unsigned short)0;
  }
  // s_pts (shadow -> 1e6)
  if (tid < NNB*4){
    int m = tid >> 2, c = tid & 3;
    if (c < 3){
      int ix = inds[(size_t)n*NNB + m];
      sptsA[tid] = (ix < NSUP) ? s_pts[(size_t)ix*3 + c] : 1e6f;
    } else sptsA[tid] = 0.f;
  }

  // x prefetch: B-frag values for weighted MFMA, nf=0,1 (x channels)
  float xv[16];
  #pragma unroll
  for (int nf = 0; nf < 2; nf++){
    int ch = wid*32 + nf*16 + fr;
    #pragma unroll
    for (int j = 0; j < 8; j++){
      int ix = __shfl(idxr, mg*8 + j);
      float v = x[(size_t)(ix < NSUP ? ix : 0)*128 + ch];
      xv[nf*8+j] = ix < NSUP ? v : 0.f;
    }
  }

  __syncthreads();   // zeros + slrfA + sptsA visible

  // neighbor loop: statically unrolled, no global access
  #pragma unroll
  for (int it = 0; it < 8; ++it){
    const int m = wid + it*4;
    if (m < NNB){                        // wave-uniform guard
      const int idx = __shfl(idxr, m);
      const bool val = (idx < NSUP);
      f32x4 sp4 = *(const f32x4*)&sptsA[m*4];
      const float d0 = sp4[0] - qp0, d1 = sp4[1] - qp1, d2 = sp4[2] - qp2;

      if (lane < 60){
        float a0 = d0*qlw[0] + d1*qlw[3] + d2*qlw[6];
        float a1 = d0*qlw[1] + d1*qlw[4] + d2*qlw[7];
        float a2 = d0*qlw[2] + d1*qlw[5] + d2*qlw[8];
        float s0 = a0-kpx, s1 = a1-kpy, s2 = a2-kpz;
        float awv = fmaxf(0.f, 1.f - sqrtf(s0*s0+s1*s1+s2*s2)*EXTINV);
        AWs[awbase + ((((m>>3) ^ awx) << 3) | (m & 7))] = f2bf(awv);
      } else {
        int qq = lane - 60;              // bias fold at u=36 (group 4, low 4)
        A_q[qq*2048 + m*64 + (((4 ^ (m&7)) << 3) | 4)] = val ? (unsigned short)0x3F80 : (unsigned short)0;
      }

      // aligned_lrf[q][s,i,j] = sum_k ql[q,k,i]*slrf[s,k,j] -> A_q bf16 (swz)
      #pragma unroll
      for (int r = 0; r < 3; r++){
        if (acta[r]){
          const unsigned short* sp = &slrfA[m*36 + asj[r]];
          float acc = qla[r][0]*bf2f(sp[0]) + qla[r][1]*bf2f(sp[3]) + qla[r][2]*bf2f(sp[6]);
          A_q[abase[r] + m*64 + ((aug[r] ^ (m&7)) << 3)] = f2bf(acc);
        }
      }
    }
  }

  __syncthreads();   // all A_q / AWs writes visible

  // lrf-features MFMA: wave wid handles q=wid. C[32m][32c] over K=64 (2 steps)
  f32x4 cq00 = {0,0,0,0}, cq01 = cq00, cq10 = cq00, cq11 = cq00;
  #pragma unroll
  for (int step = 0; step < 2; step++){
    int g = step*4 + mg;
    bf16x8 a0 = *(const bf16x8*)&A_q[wid*2048 + (fr     )*64 + ((g ^ (fr&7)) << 3)];
    bf16x8 a1 = *(const bf16x8*)&A_q[wid*2048 + (16 + fr)*64 + ((g ^ ((16+fr)&7)) << 3)];
    cq00 = __builtin_amdgcn_mfma_f32_16x16x32_bf16(a0, wtb[step][0], cq00, 0, 0, 0);
    cq01 = __builtin_amdgcn_mfma_f32_16x16x32_bf16(a0, wtb[step][1], cq01, 0, 0, 0);
    cq10 = __builtin_amdgcn_mfma_f32_16x16x32_bf16(a1, wtb[step][0], cq10, 0, 0, 0);
    cq11 = __builtin_amdgcn_mfma_f32_16x16x32_bf16(a1, wtb[step][1], cq11, 0, 0, 0);
  }
  // scatter C -> NXT[q][c0][m] (swz by c0&3); m=30,31 rows zero via A_q pad
  #pragma unroll
  for (int mt = 0; mt < 2; mt++){
    #pragma unroll
    for (int ct = 0; ct < 2; ct++){
      f32x4 cv = (mt==0) ? (ct==0 ? cq00 : cq01) : (ct==0 ? cq10 : cq11);
      #pragma unroll
      for (int r = 0; r < 4; r++){
        int mrow = mt*16 + mg*4 + r;      // C/D: col=lane&15, row=(lane>>4)*4+r
        int c0 = ct*16 + fr;
        NXT[wid*1024 + c0*32 + ((((mrow>>3) ^ (c0&3)) << 3) | (mrow & 7))] = f2bf(cv[r]);
      }
    }
  }

  // pack x prefetch into B-fragments
  bf16x8 xf[2];
  #pragma unroll
  for (int nf = 0; nf < 2; nf++)
    #pragma unroll
    for (int j = 0; j < 8; j++)
      ((unsigned short*)&xf[nf])[j] = f2bf(xv[nf*8+j]);

  asm volatile("s_waitcnt lgkmcnt(0)" ::: "memory");  // NXT scatter visible (wave-internal)

  // weighted MFMA: D[k][c] = sum_m AW[q*16+k][m] * NX[m][c]
  const int arow = wid*16 + fr;
  bf16x8 awf = *(const bf16x8*)&AWs[arow*32 + ((mg ^ (arow&3)) << 3)];
  const size_t base = (size_t)blockIdx.x * KF;
  #pragma unroll
  for (int nf = 0; nf < 4; nf++){
    bf16x8 bf_;
    if (nf < 2){
      bf_ = xf[nf];
    } else {
      int c0 = (nf-2)*16 + fr;
      bf_ = *(const bf16x8*)&NXT[wid*1024 + c0*32 + ((mg ^ (c0&3)) << 3)];
    }
    f32x4 z = {0,0,0,0};
    f32x4 d = __builtin_amdgcn_mfma_f32_16x16x32_bf16(awf, bf_, z, 0, 0, 0);
    #pragma unroll
    for (int r = 0; r < 4; r++){
      int k = mg*4 + r;
      if (k < NKP)
        wsA[base + k*256 + wid*64 + nf*16 + fr] = f2bf(d[r]);
    }
  }
}

// ---------------------------------------------------------------------------
// Phase C v5: BM=32, BN=128, BK=32, 256 thr / 4 waves (each 32m x 32n).
// grid = (padM/32, 2) ~ 1256 blocks -> ~5 blocks/CU of TLP hides the
// per-K-step drain. LDS 20KB double-buffered, global_load_lds staging.
// ---------------------------------------------------------------------------
__global__ __launch_bounds__(256, 6) void gemm_out_v5(
    const unsigned short* __restrict__ A,   // [padM][3840] bf16
    const unsigned short* __restrict__ Bt,  // [256][3840] bf16
    const float* __restrict__ bias,
    float* __restrict__ out, int n0)
{
  __shared__ __align__(16) unsigned short As[2][32*32];    // 2KB each
  __shared__ __align__(16) unsigned short Bs[2][128*32];   // 8KB each
  const int tid = threadIdx.x, lane = tid & 63, wid = tid >> 6;
  const int fr = lane & 15, mg = lane >> 4;
  const int m0 = blockIdx.x * 32;
  const int o0 = blockIdx.y * 128;

  const unsigned short* aSrc = A  + (size_t)(m0 + (tid>>2))*KF + (tid&3)*8;       // tid<128
  const unsigned short* bSrc0 = Bt + (size_t)(o0 + (tid>>2))*KF + (tid&3)*8;      // rows 0..63
  const unsigned short* bSrc1 = Bt + (size_t)(o0 + 64 + (tid>>2))*KF + (tid&3)*8; // rows 64..127

  f32x4 acc[2][2];
  #pragma unroll
  for (int i = 0; i < 2; i++)
    #pragma unroll
    for (int j = 0; j < 2; j++){ f32x4 z = {0,0,0,0}; acc[i][j] = z; }

  #define STG(buf, k0)                                                  \
    do {                                                                \
      if (tid < 128) gl_lds16(aSrc + (k0), &As[buf][tid*8]);            \
      gl_lds16(bSrc0 + (k0), &Bs[buf][tid*8]);                          \
      gl_lds16(bSrc1 + (k0), &Bs[buf][2048 + tid*8]);                   \
    } while (0)

  STG(0, 0);
  asm volatile("s_waitcnt vmcnt(0)" ::: "memory");
  __syncthreads();

  int cur = 0;
  for (int t = 0; t < KF/32; ++t){
    if (t + 1 < KF/32) STG(cur^1, (t+1)*32);
    bf16x8 af[2], bf[2];
    #pragma unroll
    for (int mf = 0; mf < 2; mf++) af[mf] = *(const bf16x8*)&As[cur][(mf*16 + fr)*32 + mg*8];
    #pragma unroll
    for (int nf = 0; nf < 2; nf++) bf[nf] = *(const bf16x8*)&Bs[cur][(wid*32 + nf*16 + fr)*32 + mg*8];
    #pragma unroll
    for (int mf = 0; mf < 2; mf++)
      #pragma unroll
      for (int nf = 0; nf < 2; nf++)
        acc[mf][nf] = __builtin_amdgcn_mfma_f32_16x16x32_bf16(af[mf], bf[nf], acc[mf][nf], 0, 0, 0);
    asm volatile("s_waitcnt vmcnt(0)" ::: "memory");
    __syncthreads();
    cur ^= 1;
  }
  #undef STG

  float bv[2];
  #pragma unroll
  for (int nf = 0; nf < 2; nf++) bv[nf] = bias[o0 + wid*32 + nf*16 + fr];
  #pragma unroll
  for (int mf = 0; mf < 2; mf++){
    #pragma unroll
    for (int nf = 0; nf < 2; nf++){
      #pragma unroll
      for (int r = 0; r < 4; r++){
        int row = mf*16 + mg*4 + r;        // C/D: col=lane&15, row=(lane>>4)*4+r
        int n_g = n0 + m0 + row;
        if (n_g < NQPTS){
          int o = o0 + wid*32 + nf*16 + fr;
          float v = acc[mf][nf][r] + bv[nf];
          out[(size_t)n_g*256 + o] = (v >= 0.f) ? v : 0.1f*v;
        }
      }
    }
  }
}

// ---------------------------------------------------------------------------
extern "C" void kernel_launch(void* const* d_in, const int* in_sizes, int n_in,
                              void* d_out, int out_size, void* d_ws, size_t ws_size,
                              hipStream_t stream)
{
  const float* q_pts = (const float*)d_in[0];
  const float* s_pts = (const float*)d_in[1];
  const int*   inds  = (const int*)  d_in[2];
  const float* x     = (const float*)d_in[3];
  const float* q_lrf = (const float*)d_in[4];
  const float* s_lrf = (const float*)d_in[5];
  const float* kp    = (const float*)d_in[6];
  const float* wts   = (const float*)d_in[7];
  const float* Wlrf  = (const float*)d_in[8];
  const float* blrf  = (const float*)d_in[9];
  const float* bias  = (const float*)d_in[10];
  float* out = (float*)d_out;

  const size_t BBYTES  = (size_t)256 * KF * sizeof(unsigned short); // 1.97 MB
  const size_t WTBYTES = 4096;
  unsigned short* wsB  = (unsigned short*)d_ws;
  unsigned short* wtf  = (unsigned short*)((char*)d_ws + BBYTES);
  unsigned short* wsA  = (unsigned short*)((char*)d_ws + BBYTES + WTBYTES);

  size_t used = BBYTES + WTBYTES;
  size_t avail = (ws_size > used) ? (ws_size - used) : 0;
  long maxRows = (long)(avail / ((size_t)KF * sizeof(unsigned short)));
  long chunk = (maxRows / 128) * 128;
  if (chunk > 20096) chunk = 20096;
  if (chunk < 128)   chunk = 128;   // last-resort; assumes ws >= ~2.5 MB

  convert_wt<<<dim3(30, 4), 256, 0, stream>>>(wts, wsB);
  prep_wtfrag<<<1, 64, 0, stream>>>(Wlrf, blrf, wtf);

  for (long n0 = 0; n0 < NQPTS; n0 += chunk){
    long rows = NQPTS - n0; if (rows > chunk) rows = chunk;
    long padM = ((rows + 31)/32)*32;
    build_weighted_v5<<<(int)rows, 256, 0, stream>>>(q_pts, s_pts, inds, x,
        q_lrf, s_lrf, kp, wtf, wsA, (int)n0);
    gemm_out_v5<<<dim3((int)(padM/32), 2), 256, 0, stream>>>(wsA, wsB, bias, out, (int)n0);
  }
}